// Round 3
// baseline (38.127 us; speedup 1.0000x reference)
//
#include <hip/hip_runtime.h>

#define NBATCH 8
#define NPB 4096                  // points per batch per cloud
#define NPTS 32768                // points per cloud, all batches
#define STRIPS 64                 // row strips of 64 (2 x 32) per batch
#define JQ 4                      // col quarters (one per wave)
#define JSTEPS 32                 // 32 cols per step -> 1024 cols per wave
#define THREADS 256
#define ONEBF 0x3F80u
#define ROLE_HALF_BYTES ((size_t)NPTS * 16)       // 512 KB
#define ROLE_BYTES (2 * ROLE_HALF_BYTES)          // 1 MB
#define FRAG_BYTES (4 * ROLE_BYTES)               // 4 MB
#define COLMIN_FLOATS ((size_t)2 * NBATCH * STRIPS * NPB)   // 4.19M -> 16 MB
#define SCALE2 (2.0f / 32768.0f)  // dist = 2*S, mean over B*N per direction

typedef short short8 __attribute__((ext_vector_type(8)));
typedef float f32x16 __attribute__((ext_vector_type(16)));

__device__ __forceinline__ unsigned short bf16rn(float x) {
  unsigned int u = __float_as_uint(x);
  unsigned int r = (u + 0x7fffu + ((u >> 16) & 1u)) >> 16;
  return (unsigned short)r;
}
__device__ __forceinline__ float bf16tof(unsigned short h) {
  return __uint_as_float(((unsigned int)h) << 16);
}
__device__ __forceinline__ uint4 pack8(unsigned short s0, unsigned short s1,
                                       unsigned short s2, unsigned short s3,
                                       unsigned short s4, unsigned short s5,
                                       unsigned short s6, unsigned short s7) {
  uint4 r;
  r.x = (unsigned)s0 | ((unsigned)s1 << 16);
  r.y = (unsigned)s2 | ((unsigned)s3 << 16);
  r.z = (unsigned)s4 | ((unsigned)s5 << 16);
  r.w = (unsigned)s6 | ((unsigned)s7 << 16);
  return r;
}
__device__ __forceinline__ float m3(float a, float b, float c) {
  return fminf(fminf(a, b), c);   // v_min3_f32 bait
}

__device__ __forceinline__ float blockReduceSum(float v) {
  #pragma unroll
  for (int off = 32; off > 0; off >>= 1)
    v += __shfl_down(v, off, 64);
  __shared__ float smem[THREADS / 64];
  int lane = threadIdx.x & 63;
  int wid  = threadIdx.x >> 6;
  if (lane == 0) smem[wid] = v;
  __syncthreads();
  float r = 0.f;
  if (threadIdx.x == 0) {
    #pragma unroll
    for (int w = 0; w < THREADS / 64; ++w) r += smem[w];
  }
  return r;
}

// ---------------- kernel 1: build bf16-split fragment planes -----------------
// S[n,m] = (|p|^2+|t|^2)/2 - p.t  via 13 K-slots:
// A (row role): [hx,hy,hz, lx,ly,lz, hx,hy | hz, nh, nl, 1, 1, 0,0,0]
// B (col role): [-hx,-hy,-hz, -hx,-hy,-hz, -lx,-ly | -lz, 1, 1, nh, nl, 0,0,0]
// roles in ws: 0=predA 1=tgtA 2=predB 3=tgtB; each role = [half][pt][16B].
__global__ __launch_bounds__(THREADS)
void chamfer_prep_kernel(const float* __restrict__ pred,
                         const float* __restrict__ tgt,
                         unsigned char* __restrict__ ws,
                         float* __restrict__ out) {
  int id = blockIdx.x * THREADS + (int)threadIdx.x;   // 0..65535
  if (id == 0) out[0] = 0.0f;
  int cloud = id >> 15;
  int pt = id & (NPTS - 1);
  const float* s = (cloud ? tgt : pred) + (size_t)pt * 3;
  float x = s[0], y = s[1], z = s[2];
  unsigned short hx = bf16rn(x), hy = bf16rn(y), hz = bf16rn(z);
  unsigned short lx = bf16rn(x - bf16tof(hx));
  unsigned short ly = bf16rn(y - bf16tof(hy));
  unsigned short lz = bf16rn(z - bf16tof(hz));
  float nq = 0.5f * (x * x + y * y + z * z);
  unsigned short nh = bf16rn(nq);
  unsigned short nl = bf16rn(nq - bf16tof(nh));
  unsigned short mhx = hx ^ 0x8000u, mhy = hy ^ 0x8000u, mhz = hz ^ 0x8000u;
  unsigned short mlx = lx ^ 0x8000u, mly = ly ^ 0x8000u, mlz = lz ^ 0x8000u;

  uint4 a0 = pack8(hx, hy, hz, lx, ly, lz, hx, hy);
  uint4 a1 = pack8(hz, nh, nl, ONEBF, ONEBF, 0, 0, 0);
  uint4 b0 = pack8(mhx, mhy, mhz, mhx, mhy, mhz, mlx, mly);
  uint4 b1 = pack8(mlz, ONEBF, ONEBF, nh, nl, 0, 0, 0);

  unsigned char* pa = ws + (size_t)(cloud ? 1 : 0) * ROLE_BYTES;
  *(uint4*)(pa + (size_t)pt * 16) = a0;
  *(uint4*)(pa + ROLE_HALF_BYTES + (size_t)pt * 16) = a1;
  unsigned char* pb = ws + (size_t)(cloud ? 3 : 2) * ROLE_BYTES;
  *(uint4*)(pb + (size_t)pt * 16) = b0;
  *(uint4*)(pb + ROLE_HALF_BYTES + (size_t)pt * 16) = b1;
}

// ---------------- kernel 2: MFMA distance tiles + col-min fold ---------------
// grid = [d(2)][b(8)][strip(64)] = 1024 blocks, 4 waves; wave = col quarter.
// Each wave: rows strip*64..+63 (A side), cols jq*1024..+1023 (B side).
// Per j-step: one 32-col B-frag, two 32x32x16 MFMAs, fold 32 regs -> col min
// over 64 rows, write ws_col[d][b][strip][col].
__global__ __launch_bounds__(THREADS)
void chamfer_minmat_kernel(const unsigned char* __restrict__ ws,
                           float* __restrict__ wscol) {
  int bid = (int)blockIdx.x;
  int strip = bid & 63;
  int b = (bid >> 6) & 7;
  int d = bid >> 9;
  int lane = (int)threadIdx.x & 63;
  int jq = (int)threadIdx.x >> 6;
  int l31 = lane & 31;
  int half = lane >> 5;

  // dir 0: per-PRED-point min over TARGET points -> cols=pred, rows=target
  const unsigned char* planeA = ws + (size_t)(d == 0 ? 1 : 0) * ROLE_BYTES;
  const unsigned char* planeB = ws + (size_t)(d == 0 ? 2 : 3) * ROLE_BYTES;

  size_t hoff = (size_t)half * ROLE_HALF_BYTES;
  int rowpt = b * NPB + strip * 64 + l31;
  short8 a0 = *(const short8*)(planeA + hoff + (size_t)rowpt * 16);
  short8 a1 = *(const short8*)(planeA + hoff + (size_t)(rowpt + 32) * 16);

  int col0 = jq * (JSTEPS * 32);
  const unsigned char* bptr = planeB + hoff + (size_t)(b * NPB + col0 + l31) * 16;
  float* wout = wscol + ((size_t)(d * NBATCH + b) * STRIPS + strip) * NPB + col0 + l31;

  f32x16 zero = {};

  #pragma unroll 2
  for (int js = 0; js < JSTEPS; ++js) {
    short8 bf = *(const short8*)(bptr + (size_t)js * (32 * 16));
    f32x16 c0 = __builtin_amdgcn_mfma_f32_32x32x16_bf16(a0, bf, zero, 0, 0, 0);
    f32x16 c1 = __builtin_amdgcn_mfma_f32_32x32x16_bf16(a1, bf, zero, 0, 0, 0);
    // fold 32 values (rows of this half) with min3 trees
    float p0 = m3(c0[0], c0[1], c0[2]);
    float p1 = m3(c0[3], c0[4], c0[5]);
    float p2 = m3(c0[6], c0[7], c0[8]);
    float p3 = m3(c0[9], c0[10], c0[11]);
    float p4 = m3(c0[12], c0[13], c0[14]);
    float p5 = m3(c0[15], c1[0], c1[1]);
    float p6 = m3(c1[2], c1[3], c1[4]);
    float p7 = m3(c1[5], c1[6], c1[7]);
    float p8 = m3(c1[8], c1[9], c1[10]);
    float p9 = m3(c1[11], c1[12], c1[13]);
    float p10 = fminf(c1[14], c1[15]);
    float q0 = m3(p0, p1, p2);
    float q1 = m3(p3, p4, p5);
    float q2 = m3(p6, p7, p8);
    float q3 = fminf(p9, p10);
    float m = fminf(m3(q0, q1, q2), q3);
    // combine the two 32-row halves
    m = fminf(m, __shfl_xor(m, 32, 64));
    if (half == 0) wout[js * 32] = m;
  }
}

// ---------------- kernel 3: min over 64 strips, mean, sum --------------------
__global__ __launch_bounds__(THREADS)
void chamfer_reduce_kernel(const float* __restrict__ wscol,
                           float* __restrict__ out) {
  int id = (int)blockIdx.x * THREADS + (int)threadIdx.x;   // 2*8*4096 = 65536
  const float* src = wscol + (size_t)(id >> 12) * (STRIPS * NPB) + (id & (NPB - 1));
  float m0 = 1e30f, m1 = 1e30f, m2 = 1e30f, m3v = 1e30f;
  #pragma unroll
  for (int s = 0; s < STRIPS; s += 4) {
    m0 = fminf(m0, src[(size_t)(s + 0) * NPB]);
    m1 = fminf(m1, src[(size_t)(s + 1) * NPB]);
    m2 = fminf(m2, src[(size_t)(s + 2) * NPB]);
    m3v = fminf(m3v, src[(size_t)(s + 3) * NPB]);
  }
  float v = fminf(fminf(m0, m1), fminf(m2, m3v));
  float ssum = blockReduceSum(v);
  if (threadIdx.x == 0) atomicAdd(out, ssum * SCALE2);
}

// ---------------- fallback (no ws): exact fp32 path from round 2 -------------
__global__ void chamfer_zero_kernel(float* out) {
  if (threadIdx.x == 0) out[0] = 0.0f;
}
__global__ __launch_bounds__(THREADS, 2)
void chamfer_fallback_kernel(const float* __restrict__ pred,
                             const float* __restrict__ tgt,
                             float* __restrict__ out) {
  const int tid = (int)threadIdx.x;
  const int bid = (int)blockIdx.x;     // 32 blocks: [dir(2)][b(8)][pc(2)]
  int pc = bid & 1, b = (bid >> 1) & 7, dir = (bid >> 4) & 1;
  const float* psrc = (dir == 0 ? pred : tgt) + (size_t)b * NPB * 3;
  const float* tsrc = (dir == 0 ? tgt : pred) + (size_t)b * NPB * 3;
  float px[8], py[8], pz[8], pp[8], bA[8], bB[8];
  int n[8];
  #pragma unroll
  for (int p = 0; p < 8; ++p) {
    n[p] = pc * (THREADS * 8) + p * THREADS + tid;
    px[p] = psrc[3 * n[p] + 0]; py[p] = psrc[3 * n[p] + 1]; pz[p] = psrc[3 * n[p] + 2];
    pp[p] = px[p] * px[p] + py[p] * py[p] + pz[p] * pz[p];
    bA[p] = 1e30f; bB[p] = 1e30f;
  }
  __shared__ float4 sh[256];
  for (int step = 0; step < 16; ++step) {
    int mbase = step * 256;
    for (int t = tid; t < 256; t += THREADS) {
      const float* q = tsrc + 3 * (size_t)(mbase + t);
      float x = q[0], y = q[1], z = q[2];
      sh[t] = make_float4(x, y, z, 0.5f * (x * x + y * y + z * z));
    }
    __syncthreads();
    for (int j = 0; j < 256; j += 4) {
      float4 t0 = sh[j], t1 = sh[j + 1], t2 = sh[j + 2], t3 = sh[j + 3];
      #pragma unroll
      for (int p = 0; p < 8; ++p) {
        float e0 = __builtin_fmaf(-px[p], t0.x, __builtin_fmaf(-py[p], t0.y, __builtin_fmaf(-pz[p], t0.z, t0.w)));
        float e1 = __builtin_fmaf(-px[p], t1.x, __builtin_fmaf(-py[p], t1.y, __builtin_fmaf(-pz[p], t1.z, t1.w)));
        float e2 = __builtin_fmaf(-px[p], t2.x, __builtin_fmaf(-py[p], t2.y, __builtin_fmaf(-pz[p], t2.z, t2.w)));
        float e3 = __builtin_fmaf(-px[p], t3.x, __builtin_fmaf(-py[p], t3.y, __builtin_fmaf(-pz[p], t3.z, t3.w)));
        bA[p] = fminf(fminf(bA[p], e0), e1);
        bB[p] = fminf(fminf(bB[p], e2), e3);
      }
    }
    __syncthreads();
  }
  float local = 0.f;
  #pragma unroll
  for (int p = 0; p < 8; ++p)
    local += fmaxf(pp[p] + 2.0f * fminf(bA[p], bB[p]), 0.0f);
  float s = blockReduceSum(local);
  if (tid == 0) atomicAdd(out, s * (1.0f / 32768.0f));
}

extern "C" void kernel_launch(void* const* d_in, const int* in_sizes, int n_in,
                              void* d_out, int out_size, void* d_ws, size_t ws_size,
                              hipStream_t stream) {
  const float* pred = (const float*)d_in[0];
  const float* tgt  = (const float*)d_in[1];
  float* out = (float*)d_out;

  const size_t ws_needed = FRAG_BYTES + COLMIN_FLOATS * sizeof(float);  // 20 MB

  if (ws_size >= ws_needed && d_ws != nullptr) {
    unsigned char* ws = (unsigned char*)d_ws;
    float* wscol = (float*)(ws + FRAG_BYTES);
    chamfer_prep_kernel<<<65536 / THREADS, THREADS, 0, stream>>>(pred, tgt, ws, out);
    chamfer_minmat_kernel<<<1024, THREADS, 0, stream>>>(ws, wscol);
    chamfer_reduce_kernel<<<65536 / THREADS, THREADS, 0, stream>>>(wscol, out);
  } else {
    chamfer_zero_kernel<<<1, 64, 0, stream>>>(out);
    chamfer_fallback_kernel<<<32, THREADS, 0, stream>>>(pred, tgt, out);
  }
}

// Round 4
// 33.858 us; speedup vs baseline: 1.1261x; 1.1261x over previous
//
#include <hip/hip_runtime.h>

#define NBATCH 8
#define NPB 4096                  // points per batch per cloud
#define NPTS 32768                // points per cloud, all batches
#define THREADS 256
#define ONEBF 0x3F80u
#define ROLE_HALF_BYTES ((size_t)NPTS * 16)       // 512 KB
#define ROLE_BYTES (2 * ROLE_HALF_BYTES)          // 1 MB
#define FRAG_BYTES (4 * ROLE_BYTES)               // 4 MB
#define SCALE2 (2.0f / 32768.0f)  // dist = 2*S, mean over B*N per direction

typedef short short8 __attribute__((ext_vector_type(8)));
typedef float f32x16 __attribute__((ext_vector_type(16)));

__device__ __forceinline__ unsigned short bf16rn(float x) {
  unsigned int u = __float_as_uint(x);
  unsigned int r = (u + 0x7fffu + ((u >> 16) & 1u)) >> 16;
  return (unsigned short)r;
}
__device__ __forceinline__ float bf16tof(unsigned short h) {
  return __uint_as_float(((unsigned int)h) << 16);
}
__device__ __forceinline__ uint4 pack8(unsigned short s0, unsigned short s1,
                                       unsigned short s2, unsigned short s3,
                                       unsigned short s4, unsigned short s5,
                                       unsigned short s6, unsigned short s7) {
  uint4 r;
  r.x = (unsigned)s0 | ((unsigned)s1 << 16);
  r.y = (unsigned)s2 | ((unsigned)s3 << 16);
  r.z = (unsigned)s4 | ((unsigned)s5 << 16);
  r.w = (unsigned)s6 | ((unsigned)s7 << 16);
  return r;
}
__device__ __forceinline__ float m3(float a, float b, float c) {
  return fminf(fminf(a, b), c);   // v_min3_f32 bait
}
__device__ __forceinline__ float fold16(f32x16 a) {
  float p0 = m3(a[0], a[1], a[2]);
  float p1 = m3(a[3], a[4], a[5]);
  float p2 = m3(a[6], a[7], a[8]);
  float p3 = m3(a[9], a[10], a[11]);
  float p4 = m3(a[12], a[13], a[14]);
  float q0 = m3(p0, p1, a[15]);
  float q1 = m3(p2, p3, p4);
  return fminf(q0, q1);
}

__device__ __forceinline__ float blockReduceSum(float v) {
  #pragma unroll
  for (int off = 32; off > 0; off >>= 1)
    v += __shfl_down(v, off, 64);
  __shared__ float smem[THREADS / 64];
  int lane = threadIdx.x & 63;
  int wid  = threadIdx.x >> 6;
  if (lane == 0) smem[wid] = v;
  __syncthreads();
  float r = 0.f;
  if (threadIdx.x == 0) {
    #pragma unroll
    for (int w = 0; w < THREADS / 64; ++w) r += smem[w];
  }
  return r;
}

// ---------------- kernel 1: build bf16-split fragment planes -----------------
// S[n,m] = (|p|^2+|t|^2)/2 - p.t  via 13 K-slots (verified round 3, absmax 0):
// A (row role): [hx,hy,hz, lx,ly,lz, hx,hy | hz, nh, nl, 1, 1, 0,0,0]
// B (col role): [-hx,-hy,-hz, -hx,-hy,-hz, -lx,-ly | -lz, 1, 1, nh, nl, 0,0,0]
// roles in ws: 0=predA 1=tgtA 2=predB 3=tgtB; each role = [half][pt][16B].
__global__ __launch_bounds__(THREADS)
void chamfer_prep_kernel(const float* __restrict__ pred,
                         const float* __restrict__ tgt,
                         unsigned char* __restrict__ ws,
                         float* __restrict__ out) {
  int id = blockIdx.x * THREADS + (int)threadIdx.x;   // 0..65535
  if (id == 0) out[0] = 0.0f;
  int cloud = id >> 15;
  int pt = id & (NPTS - 1);
  const float* s = (cloud ? tgt : pred) + (size_t)pt * 3;
  float x = s[0], y = s[1], z = s[2];
  unsigned short hx = bf16rn(x), hy = bf16rn(y), hz = bf16rn(z);
  unsigned short lx = bf16rn(x - bf16tof(hx));
  unsigned short ly = bf16rn(y - bf16tof(hy));
  unsigned short lz = bf16rn(z - bf16tof(hz));
  float nq = 0.5f * (x * x + y * y + z * z);
  unsigned short nh = bf16rn(nq);
  unsigned short nl = bf16rn(nq - bf16tof(nh));
  unsigned short mhx = hx ^ 0x8000u, mhy = hy ^ 0x8000u, mhz = hz ^ 0x8000u;
  unsigned short mlx = lx ^ 0x8000u, mly = ly ^ 0x8000u, mlz = lz ^ 0x8000u;

  uint4 a0 = pack8(hx, hy, hz, lx, ly, lz, hx, hy);
  uint4 a1 = pack8(hz, nh, nl, ONEBF, ONEBF, 0, 0, 0);
  uint4 b0 = pack8(mhx, mhy, mhz, mhx, mhy, mhz, mlx, mly);
  uint4 b1 = pack8(mlz, ONEBF, ONEBF, nh, nl, 0, 0, 0);

  unsigned char* pa = ws + (size_t)(cloud ? 1 : 0) * ROLE_BYTES;
  *(uint4*)(pa + (size_t)pt * 16) = a0;
  *(uint4*)(pa + ROLE_HALF_BYTES + (size_t)pt * 16) = a1;
  unsigned char* pb = ws + (size_t)(cloud ? 3 : 2) * ROLE_BYTES;
  *(uint4*)(pb + (size_t)pt * 16) = b0;
  *(uint4*)(pb + ROLE_HALF_BYTES + (size_t)pt * 16) = b1;
}

// ---------------- kernel 2: col-stationary MFMA min, full fuse ---------------
// grid = [d(2)][b(8)][cg(32)] = 512 blocks x 4 waves.
// wave w: col pair jp = w>>1 (64 cols, B-frags in regs), row half rh = w&1
// (2048 rows, 32 steps of 64). acc = running col-min in registers; fold +
// shfl + cross-wave LDS min + block mean-sum ONCE at the end. No wscol.
__global__ __launch_bounds__(THREADS)
void chamfer_main_kernel(const unsigned char* __restrict__ ws,
                         float* __restrict__ out) {
  int bid = (int)blockIdx.x;
  int cg = bid & 31;
  int b  = (bid >> 5) & 7;
  int d  = bid >> 8;
  int tid = (int)threadIdx.x;
  int w    = tid >> 6;
  int lane = tid & 63;
  int l31  = lane & 31;
  int half = lane >> 5;
  int jp = w >> 1;
  int rh = w & 1;

  // dir 0: per-PRED-point min over TARGET points -> cols=pred, rows=target
  const unsigned char* planeA = ws + (size_t)(d == 0 ? 1 : 0) * ROLE_BYTES;
  const unsigned char* planeB = ws + (size_t)(d == 0 ? 2 : 3) * ROLE_BYTES;
  size_t hoff = (size_t)half * ROLE_HALF_BYTES;

  int colbase = cg * 128 + jp * 64;
  const unsigned char* bp = planeB + hoff + (size_t)(b * NPB + colbase + l31) * 16;
  short8 bf0 = *(const short8*)(bp);
  short8 bf1 = *(const short8*)(bp + 32 * 16);

  const unsigned char* ap =
      planeA + hoff + (size_t)(b * NPB + rh * 2048 + l31) * 16;

  f32x16 acc0, acc1;
  #pragma unroll
  for (int i = 0; i < 16; ++i) { acc0[i] = 1e30f; acc1[i] = 1e30f; }

  f32x16 zero = {};
  #pragma unroll 2
  for (int step = 0; step < 32; ++step) {
    const unsigned char* a = ap + (size_t)step * (64 * 16);
    short8 af0 = *(const short8*)(a);
    short8 af1 = *(const short8*)(a + 32 * 16);
    f32x16 c00 = __builtin_amdgcn_mfma_f32_32x32x16_bf16(af0, bf0, zero, 0, 0, 0);
    f32x16 c10 = __builtin_amdgcn_mfma_f32_32x32x16_bf16(af1, bf0, zero, 0, 0, 0);
    f32x16 c01 = __builtin_amdgcn_mfma_f32_32x32x16_bf16(af0, bf1, zero, 0, 0, 0);
    f32x16 c11 = __builtin_amdgcn_mfma_f32_32x32x16_bf16(af1, bf1, zero, 0, 0, 0);
    #pragma unroll
    for (int i = 0; i < 16; ++i) {
      acc0[i] = m3(acc0[i], c00[i], c10[i]);
      acc1[i] = m3(acc1[i], c01[i], c11[i]);
    }
  }

  float m0 = fold16(acc0);                    // min over this half's row group
  float m1 = fold16(acc1);
  m0 = fminf(m0, __shfl_xor(m0, 32, 64));     // combine row-parity halves
  m1 = fminf(m1, __shfl_xor(m1, 32, 64));

  __shared__ float cmin[4][64];
  if (half == 0) {
    cmin[w][l31] = m0;                        // cols colbase + l31
    cmin[w][32 + l31] = m1;                   // cols colbase + 32 + l31
  }
  __syncthreads();

  float v = 0.f;
  if (tid < 128) {                            // 128 cols of this block
    int p = tid >> 6;                         // col pair (waves 2p, 2p+1)
    int cc = tid & 63;
    float mm = fminf(cmin[2 * p][cc], cmin[2 * p + 1][cc]);
    v = fmaxf(mm, 0.0f);
  }
  float s = blockReduceSum(v);
  if (tid == 0) atomicAdd(out, s * SCALE2);
}

// ---------------- fallback (no ws): exact fp32 path from round 2 -------------
__global__ void chamfer_zero_kernel(float* out) {
  if (threadIdx.x == 0) out[0] = 0.0f;
}
__global__ __launch_bounds__(THREADS, 2)
void chamfer_fallback_kernel(const float* __restrict__ pred,
                             const float* __restrict__ tgt,
                             float* __restrict__ out) {
  const int tid = (int)threadIdx.x;
  const int bid = (int)blockIdx.x;     // 32 blocks: [dir(2)][b(8)][pc(2)]
  int pc = bid & 1, b = (bid >> 1) & 7, dir = (bid >> 4) & 1;
  const float* psrc = (dir == 0 ? pred : tgt) + (size_t)b * NPB * 3;
  const float* tsrc = (dir == 0 ? tgt : pred) + (size_t)b * NPB * 3;
  float px[8], py[8], pz[8], pp[8], bA[8], bB[8];
  int n[8];
  #pragma unroll
  for (int p = 0; p < 8; ++p) {
    n[p] = pc * (THREADS * 8) + p * THREADS + tid;
    px[p] = psrc[3 * n[p] + 0]; py[p] = psrc[3 * n[p] + 1]; pz[p] = psrc[3 * n[p] + 2];
    pp[p] = px[p] * px[p] + py[p] * py[p] + pz[p] * pz[p];
    bA[p] = 1e30f; bB[p] = 1e30f;
  }
  __shared__ float4 sh[256];
  for (int step = 0; step < 16; ++step) {
    int mbase = step * 256;
    for (int t = tid; t < 256; t += THREADS) {
      const float* q = tsrc + 3 * (size_t)(mbase + t);
      float x = q[0], y = q[1], z = q[2];
      sh[t] = make_float4(x, y, z, 0.5f * (x * x + y * y + z * z));
    }
    __syncthreads();
    for (int j = 0; j < 256; j += 4) {
      float4 t0 = sh[j], t1 = sh[j + 1], t2 = sh[j + 2], t3 = sh[j + 3];
      #pragma unroll
      for (int p = 0; p < 8; ++p) {
        float e0 = __builtin_fmaf(-px[p], t0.x, __builtin_fmaf(-py[p], t0.y, __builtin_fmaf(-pz[p], t0.z, t0.w)));
        float e1 = __builtin_fmaf(-px[p], t1.x, __builtin_fmaf(-py[p], t1.y, __builtin_fmaf(-pz[p], t1.z, t1.w)));
        float e2 = __builtin_fmaf(-px[p], t2.x, __builtin_fmaf(-py[p], t2.y, __builtin_fmaf(-pz[p], t2.z, t2.w)));
        float e3 = __builtin_fmaf(-px[p], t3.x, __builtin_fmaf(-py[p], t3.y, __builtin_fmaf(-pz[p], t3.z, t3.w)));
        bA[p] = fminf(fminf(bA[p], e0), e1);
        bB[p] = fminf(fminf(bB[p], e2), e3);
      }
    }
    __syncthreads();
  }
  float local = 0.f;
  #pragma unroll
  for (int p = 0; p < 8; ++p)
    local += fmaxf(pp[p] + 2.0f * fminf(bA[p], bB[p]), 0.0f);
  float s = blockReduceSum(local);
  if (tid == 0) atomicAdd(out, s * (1.0f / 32768.0f));
}

extern "C" void kernel_launch(void* const* d_in, const int* in_sizes, int n_in,
                              void* d_out, int out_size, void* d_ws, size_t ws_size,
                              hipStream_t stream) {
  const float* pred = (const float*)d_in[0];
  const float* tgt  = (const float*)d_in[1];
  float* out = (float*)d_out;

  if (ws_size >= FRAG_BYTES && d_ws != nullptr) {
    unsigned char* ws = (unsigned char*)d_ws;
    chamfer_prep_kernel<<<NPTS * 2 / THREADS, THREADS, 0, stream>>>(pred, tgt, ws, out);
    chamfer_main_kernel<<<512, THREADS, 0, stream>>>(ws, out);
  } else {
    chamfer_zero_kernel<<<1, 64, 0, stream>>>(out);
    chamfer_fallback_kernel<<<32, THREADS, 0, stream>>>(pred, tgt, out);
  }
}

// Round 5
// 26.568 us; speedup vs baseline: 1.4351x; 1.2744x over previous
//
#include <hip/hip_runtime.h>

#define NBATCH 8
#define NPB 4096                  // points per batch per cloud
#define THREADS 256
#define ONEBF 0x3F80u
#define SCALE2 (2.0f / 32768.0f)  // dist = 2*S, mean over B*N per direction

typedef short short8 __attribute__((ext_vector_type(8)));
typedef float f32x16 __attribute__((ext_vector_type(16)));

__device__ __forceinline__ unsigned short bf16rn(float x) {
  unsigned int u = __float_as_uint(x);
  unsigned int r = (u + 0x7fffu + ((u >> 16) & 1u)) >> 16;
  return (unsigned short)r;
}
__device__ __forceinline__ float bf16tof(unsigned short h) {
  return __uint_as_float(((unsigned int)h) << 16);
}
__device__ __forceinline__ uint4 pack8(unsigned short s0, unsigned short s1,
                                       unsigned short s2, unsigned short s3,
                                       unsigned short s4, unsigned short s5,
                                       unsigned short s6, unsigned short s7) {
  uint4 r;
  r.x = (unsigned)s0 | ((unsigned)s1 << 16);
  r.y = (unsigned)s2 | ((unsigned)s3 << 16);
  r.z = (unsigned)s4 | ((unsigned)s5 << 16);
  r.w = (unsigned)s6 | ((unsigned)s7 << 16);
  return r;
}
__device__ __forceinline__ float m3(float a, float b, float c) {
  return fminf(fminf(a, b), c);   // v_min3_f32 bait
}
__device__ __forceinline__ float fold16(f32x16 a) {
  float p0 = m3(a[0], a[1], a[2]);
  float p1 = m3(a[3], a[4], a[5]);
  float p2 = m3(a[6], a[7], a[8]);
  float p3 = m3(a[9], a[10], a[11]);
  float p4 = m3(a[12], a[13], a[14]);
  float q0 = m3(p0, p1, a[15]);
  float q1 = m3(p2, p3, p4);
  return fminf(q0, q1);
}

__device__ __forceinline__ float blockReduceSum(float v) {
  #pragma unroll
  for (int off = 32; off > 0; off >>= 1)
    v += __shfl_down(v, off, 64);
  __shared__ float smem[THREADS / 64];
  int lane = threadIdx.x & 63;
  int wid  = threadIdx.x >> 6;
  if (lane == 0) smem[wid] = v;
  __syncthreads();
  float r = 0.f;
  if (threadIdx.x == 0) {
    #pragma unroll
    for (int w = 0; w < THREADS / 64; ++w) r += smem[w];
  }
  return r;
}

// ------------- fused kernel: in-block prep -> LDS A-frags -> MFMA min --------
// S[n,m] = (|p|^2+|t|^2)/2 - p.t  via 13 bf16-split K-slots (verified r3/r4):
// A half0: [hx,hy,hz, lx,ly,lz, hx,hy]   A half1: [hz, nh, nl, 1, 1, 0,0,0]
// B half0: [-hx,-hy,-hz,-hx,-hy,-hz,-lx,-ly]  B half1: [-lz, 1, 1, nh, nl, 0,0,0]
// grid = [d(2)][b(8)][cg(16)] = 256 blocks x 4 waves (1 block/CU, 130KB LDS).
// wave w: cols cg*256 + (w>>1)*128 + {0..127} (B-frags in regs), rows
// (w&1)*2048 + {0..2047} (A-frags from LDS). Per-block partial -> wspart.
__global__ __launch_bounds__(THREADS, 1)
void chamfer_fused_kernel(const float* __restrict__ pred,
                          const float* __restrict__ tgt,
                          float* __restrict__ wspart) {
  __shared__ unsigned char afr[2][NPB][16];   // 128 KB: [half][row][16B]
  __shared__ float cmin[4][128];

  int bid = (int)blockIdx.x;
  int cg = bid & 15;
  int b  = (bid >> 4) & 7;
  int d  = bid >> 7;
  int tid = (int)threadIdx.x;
  int w    = tid >> 6;
  int lane = tid & 63;
  int l31  = lane & 31;
  int half = lane >> 5;
  int cw = w >> 1;      // col half of block
  int rh = w & 1;       // row half of batch

  // dir 0: per-PRED-point min over TARGET -> rows = target, cols = pred
  const float* Ac = (d == 0 ? tgt : pred) + (size_t)b * NPB * 3;
  const float* Bc = (d == 0 ? pred : tgt) + (size_t)b * NPB * 3;

  // ---- phase 1a: A-frags for all 4096 rows -> LDS ----
  #pragma unroll 4
  for (int k = 0; k < 16; ++k) {
    int r = tid + k * THREADS;
    float x = Ac[3 * r + 0], y = Ac[3 * r + 1], z = Ac[3 * r + 2];
    unsigned short hx = bf16rn(x), hy = bf16rn(y), hz = bf16rn(z);
    unsigned short lx = bf16rn(x - bf16tof(hx));
    unsigned short ly = bf16rn(y - bf16tof(hy));
    unsigned short lz = bf16rn(z - bf16tof(hz));
    float nq = 0.5f * (x * x + y * y + z * z);
    unsigned short nh = bf16rn(nq);
    unsigned short nl = bf16rn(nq - bf16tof(nh));
    uint4 a0 = pack8(hx, hy, hz, lx, ly, lz, hx, hy);
    uint4 a1 = pack8(hz, nh, nl, ONEBF, ONEBF, 0, 0, 0);
    *(uint4*)&afr[0][r][0] = a0;
    *(uint4*)&afr[1][r][0] = a1;
  }

  // ---- phase 1b: B-frags for this wave's 128 cols -> registers ----
  int colbase = cg * 256 + cw * 128;
  short8 bf[4];
  #pragma unroll
  for (int j = 0; j < 4; ++j) {
    int col = colbase + j * 32 + l31;
    float x = Bc[3 * col + 0], y = Bc[3 * col + 1], z = Bc[3 * col + 2];
    unsigned short hx = bf16rn(x), hy = bf16rn(y), hz = bf16rn(z);
    unsigned short lx = bf16rn(x - bf16tof(hx));
    unsigned short ly = bf16rn(y - bf16tof(hy));
    unsigned short lz = bf16rn(z - bf16tof(hz));
    float nq = 0.5f * (x * x + y * y + z * z);
    unsigned short nh = bf16rn(nq);
    unsigned short nl = bf16rn(nq - bf16tof(nh));
    unsigned short mhx = hx ^ 0x8000u, mhy = hy ^ 0x8000u, mhz = hz ^ 0x8000u;
    unsigned short mlx = lx ^ 0x8000u, mly = ly ^ 0x8000u, mlz = lz ^ 0x8000u;
    uint4 bb = (half == 0)
        ? pack8(mhx, mhy, mhz, mhx, mhy, mhz, mlx, mly)
        : pack8(mlz, ONEBF, ONEBF, nh, nl, 0, 0, 0);
    union { uint4 u; short8 s; } cv;
    cv.u = bb;
    bf[j] = cv.s;
  }

  __syncthreads();

  // ---- phase 2: 32 row-steps, col-min accumulate in registers ----
  f32x16 acc0, acc1, acc2, acc3;
  #pragma unroll
  for (int i = 0; i < 16; ++i) {
    acc0[i] = 1e30f; acc1[i] = 1e30f; acc2[i] = 1e30f; acc3[i] = 1e30f;
  }
  f32x16 zero = {};
  const unsigned char* abase = &afr[half][rh * 2048][0];

  #pragma unroll 2
  for (int step = 0; step < 32; ++step) {
    const unsigned char* a = abase + (size_t)step * (64 * 16) + (size_t)l31 * 16;
    short8 af0 = *(const short8*)(a);
    short8 af1 = *(const short8*)(a + 32 * 16);
    f32x16 c0, c1;
    c0 = __builtin_amdgcn_mfma_f32_32x32x16_bf16(af0, bf[0], zero, 0, 0, 0);
    c1 = __builtin_amdgcn_mfma_f32_32x32x16_bf16(af1, bf[0], zero, 0, 0, 0);
    #pragma unroll
    for (int i = 0; i < 16; ++i) acc0[i] = m3(acc0[i], c0[i], c1[i]);
    c0 = __builtin_amdgcn_mfma_f32_32x32x16_bf16(af0, bf[1], zero, 0, 0, 0);
    c1 = __builtin_amdgcn_mfma_f32_32x32x16_bf16(af1, bf[1], zero, 0, 0, 0);
    #pragma unroll
    for (int i = 0; i < 16; ++i) acc1[i] = m3(acc1[i], c0[i], c1[i]);
    c0 = __builtin_amdgcn_mfma_f32_32x32x16_bf16(af0, bf[2], zero, 0, 0, 0);
    c1 = __builtin_amdgcn_mfma_f32_32x32x16_bf16(af1, bf[2], zero, 0, 0, 0);
    #pragma unroll
    for (int i = 0; i < 16; ++i) acc2[i] = m3(acc2[i], c0[i], c1[i]);
    c0 = __builtin_amdgcn_mfma_f32_32x32x16_bf16(af0, bf[3], zero, 0, 0, 0);
    c1 = __builtin_amdgcn_mfma_f32_32x32x16_bf16(af1, bf[3], zero, 0, 0, 0);
    #pragma unroll
    for (int i = 0; i < 16; ++i) acc3[i] = m3(acc3[i], c0[i], c1[i]);
  }

  // ---- tail: fold rows, combine halves, block partial sum ----
  float m0 = fold16(acc0), m1 = fold16(acc1), m2 = fold16(acc2), m3v = fold16(acc3);
  m0 = fminf(m0, __shfl_xor(m0, 32, 64));
  m1 = fminf(m1, __shfl_xor(m1, 32, 64));
  m2 = fminf(m2, __shfl_xor(m2, 32, 64));
  m3v = fminf(m3v, __shfl_xor(m3v, 32, 64));
  if (half == 0) {
    cmin[w][0 * 32 + l31] = m0;
    cmin[w][1 * 32 + l31] = m1;
    cmin[w][2 * 32 + l31] = m2;
    cmin[w][3 * 32 + l31] = m3v;
  }
  __syncthreads();

  int c = tid;                      // local col 0..255
  int p = c >> 7;                   // col-half -> wave pair (2p, 2p+1)
  int cc = c & 127;
  float mm = fminf(cmin[2 * p][cc], cmin[2 * p + 1][cc]);
  float v = fmaxf(mm, 0.0f);
  float s = blockReduceSum(v);
  if (tid == 0) wspart[bid] = s;
}

// ------------- final: deterministic 256 -> 1 reduction -----------------------
__global__ __launch_bounds__(THREADS)
void chamfer_final_kernel(const float* __restrict__ wspart,
                          float* __restrict__ out) {
  float v = wspart[threadIdx.x];
  float s = blockReduceSum(v);
  if (threadIdx.x == 0) out[0] = s * SCALE2;
}

// ---------------- fallback (no ws): exact fp32 path from round 2 -------------
__global__ void chamfer_zero_kernel(float* out) {
  if (threadIdx.x == 0) out[0] = 0.0f;
}
__global__ __launch_bounds__(THREADS, 2)
void chamfer_fallback_kernel(const float* __restrict__ pred,
                             const float* __restrict__ tgt,
                             float* __restrict__ out) {
  const int tid = (int)threadIdx.x;
  const int bid = (int)blockIdx.x;     // 32 blocks: [dir(2)][b(8)][pc(2)]
  int pc = bid & 1, b = (bid >> 1) & 7, dir = (bid >> 4) & 1;
  const float* psrc = (dir == 0 ? pred : tgt) + (size_t)b * NPB * 3;
  const float* tsrc = (dir == 0 ? tgt : pred) + (size_t)b * NPB * 3;
  float px[8], py[8], pz[8], pp[8], bA[8], bB[8];
  int n[8];
  #pragma unroll
  for (int p = 0; p < 8; ++p) {
    n[p] = pc * (THREADS * 8) + p * THREADS + tid;
    px[p] = psrc[3 * n[p] + 0]; py[p] = psrc[3 * n[p] + 1]; pz[p] = psrc[3 * n[p] + 2];
    pp[p] = px[p] * px[p] + py[p] * py[p] + pz[p] * pz[p];
    bA[p] = 1e30f; bB[p] = 1e30f;
  }
  __shared__ float4 sh[256];
  for (int step = 0; step < 16; ++step) {
    int mbase = step * 256;
    for (int t = tid; t < 256; t += THREADS) {
      const float* q = tsrc + 3 * (size_t)(mbase + t);
      float x = q[0], y = q[1], z = q[2];
      sh[t] = make_float4(x, y, z, 0.5f * (x * x + y * y + z * z));
    }
    __syncthreads();
    for (int j = 0; j < 256; j += 4) {
      float4 t0 = sh[j], t1 = sh[j + 1], t2 = sh[j + 2], t3 = sh[j + 3];
      #pragma unroll
      for (int p = 0; p < 8; ++p) {
        float e0 = __builtin_fmaf(-px[p], t0.x, __builtin_fmaf(-py[p], t0.y, __builtin_fmaf(-pz[p], t0.z, t0.w)));
        float e1 = __builtin_fmaf(-px[p], t1.x, __builtin_fmaf(-py[p], t1.y, __builtin_fmaf(-pz[p], t1.z, t1.w)));
        float e2 = __builtin_fmaf(-px[p], t2.x, __builtin_fmaf(-py[p], t2.y, __builtin_fmaf(-pz[p], t2.z, t2.w)));
        float e3 = __builtin_fmaf(-px[p], t3.x, __builtin_fmaf(-py[p], t3.y, __builtin_fmaf(-pz[p], t3.z, t3.w)));
        bA[p] = fminf(fminf(bA[p], e0), e1);
        bB[p] = fminf(fminf(bB[p], e2), e3);
      }
    }
    __syncthreads();
  }
  float local = 0.f;
  #pragma unroll
  for (int p = 0; p < 8; ++p)
    local += fmaxf(pp[p] + 2.0f * fminf(bA[p], bB[p]), 0.0f);
  float s = blockReduceSum(local);
  if (tid == 0) atomicAdd(out, s * (1.0f / 32768.0f));
}

extern "C" void kernel_launch(void* const* d_in, const int* in_sizes, int n_in,
                              void* d_out, int out_size, void* d_ws, size_t ws_size,
                              hipStream_t stream) {
  const float* pred = (const float*)d_in[0];
  const float* tgt  = (const float*)d_in[1];
  float* out = (float*)d_out;

  const size_t ws_needed = 256 * sizeof(float);

  if (ws_size >= ws_needed && d_ws != nullptr) {
    float* wspart = (float*)d_ws;
    chamfer_fused_kernel<<<256, THREADS, 0, stream>>>(pred, tgt, wspart);
    chamfer_final_kernel<<<1, THREADS, 0, stream>>>(wspart, out);
  } else {
    chamfer_zero_kernel<<<1, 64, 0, stream>>>(out);
    chamfer_fallback_kernel<<<32, THREADS, 0, stream>>>(pred, tgt, out);
  }
}